// Round 1
// baseline (558.468 us; speedup 1.0000x reference)
//
#include <hip/hip_runtime.h>

#define N_NODES 100000
#define N_EDGES 1200000
#define DIM     64
#define N_LAYERS 3
#define N_GRAPHS 512
#define OUTD    192   // 3 * 64, concat layout
#define BN_EPS  1e-5f

#define NPB 64            // nodes per block in layer_kernel
#define LDS_PITCH 65      // +1 pad -> 2-way bank aliasing only (free)
#define NLBLK ((N_NODES + NPB - 1) / NPB)                 // 1563

// ---- two-level binning geometry ----
#define BSHIFT 9
#define BUCK_NODES (1 << BSHIFT)                          // 512 nodes / bucket
#define NBUK ((N_NODES + BUCK_NODES - 1) / BUCK_NODES)    // 196
#define EPB 4096                                          // edges per partition block
#define NPBLK ((N_EDGES + EPB - 1) / EPB)                 // 293

// ---------------------------------------------------------------------------
// Transpose W1/W2 (per layer): WT[l][k][j] = W[l][j][k]. Also writes the
// identity affine block (scale=1, shift=0) used by layer 0.
__global__ void transpose_w(const float* __restrict__ W1, const float* __restrict__ W2,
                            float* __restrict__ W1T, float* __restrict__ W2T,
                            float* __restrict__ idaff) {
    int idx = blockIdx.x * blockDim.x + threadIdx.x;  // L*64*64
    if (idx < 128) idaff[idx] = (idx < 64) ? 1.0f : 0.0f;
    if (idx >= N_LAYERS * DIM * DIM) return;
    int l = idx >> 12;
    int r = idx & 4095;
    int j = r >> 6;
    int k = r & 63;
    int dstp = (l << 12) + k * DIM + j;
    W1T[dstp] = W1[idx];
    W2T[dstp] = W2[idx];
}

// ---------------------------------------------------------------------------
// Phase A: per-block bucket histogram (LDS atomics only, no global atomics).
// Replaces the random-8B-scatter edge_bin_ell (91us @ 8x write amp, R-prev).
__global__ void __launch_bounds__(256) part_hist(const int* __restrict__ dst,
                                                 int* __restrict__ hist) {
    __shared__ int h[NBUK];
    int t = threadIdx.x;
    if (t < NBUK) h[t] = 0;
    __syncthreads();
    int base = blockIdx.x * EPB;
    for (int i = t; i < EPB; i += 256) {
        int e = base + i;
        if (e < N_EDGES) atomicAdd(&h[dst[e] >> BSHIFT], 1);
    }
    __syncthreads();
    if (t < NBUK) hist[blockIdx.x * NBUK + t] = h[t];
}

// ---------------------------------------------------------------------------
// Phase B: per-(block,bucket) exclusive bases + bucket starts. One block;
// thread b owns bucket b (coalesced column reads across threads).
__global__ void __launch_bounds__(256) part_scan(const int* __restrict__ hist,
                                                 int* __restrict__ base,
                                                 int* __restrict__ bstart) {
    __shared__ int tot[256];
    int b = threadIdx.x;
    int run = 0;
    if (b < NBUK) {
        for (int k = 0; k < NPBLK; ++k) {
            base[k * NBUK + b] = run;
            run += hist[k * NBUK + b];
        }
    }
    tot[b] = (b < NBUK) ? run : 0;
    __syncthreads();
    int v = tot[b];
    for (int o = 1; o < 256; o <<= 1) {
        int add = (b >= o) ? tot[b - o] : 0;
        __syncthreads();
        tot[b] += add;
        __syncthreads();
    }
    int excl = tot[b] - v;   // exclusive bucket start
    if (b < NBUK) {
        bstart[b] = excl;
        for (int k = 0; k < NPBLK; ++k) base[k * NBUK + b] += excl;
        if (b == NBUK - 1) bstart[NBUK] = excl + v;   // == N_EDGES
    }
}

// ---------------------------------------------------------------------------
// Phase C: scatter edges into bucket-partitioned order. Each (block,bucket)
// range is disjoint (deterministic bases), LDS cursors only. Packs
// (src | dstLocal<<17, w) into one int2 (src<2^17, dstLocal<2^9).
__global__ void __launch_bounds__(256) part_scatter(
        const int* __restrict__ src, const int* __restrict__ dst,
        const float* __restrict__ ew, const int* __restrict__ base,
        int2* __restrict__ pp) {
    __shared__ int cur[NBUK];
    int t = threadIdx.x;
    if (t < NBUK) cur[t] = base[blockIdx.x * NBUK + t];
    __syncthreads();
    int bb = blockIdx.x * EPB;
    for (int i = t; i < EPB; i += 256) {
        int e = bb + i;
        if (e < N_EDGES) {
            int d = dst[e];
            int bk = d >> BSHIFT;
            int pos = atomicAdd(&cur[bk], 1);
            int dl = d & (BUCK_NODES - 1);
            pp[pos] = make_int2(src[e] | (dl << 17), __float_as_int(ew[e]));
        }
    }
}

// ---------------------------------------------------------------------------
// Phase D: per-bucket counting sort -> CSR. All scattered writes confined to
// the bucket's ~48KB edge window (L2-resident, dense writebacks).
__global__ void __launch_bounds__(256) csr_build(
        const int2* __restrict__ pp, const int* __restrict__ bstart,
        int* __restrict__ seg, int2* __restrict__ pe) {
    __shared__ int cnt[BUCK_NODES];
    __shared__ int ssum[256];
    int b = blockIdx.x, t = threadIdx.x;
    int ebeg = bstart[b], eend = bstart[b + 1];
    cnt[t] = 0;
    cnt[t + 256] = 0;
    __syncthreads();
    for (int e = ebeg + t; e < eend; e += 256)
        atomicAdd(&cnt[pp[e].x >> 17], 1);
    __syncthreads();
    // scan over 512 counts: thread t owns pair (2t, 2t+1)
    int c0 = cnt[2 * t], c1 = cnt[2 * t + 1];
    int ps = c0 + c1;
    ssum[t] = ps;
    __syncthreads();
    int v = ps;
    for (int o = 1; o < 256; o <<= 1) {
        int add = (t >= o) ? ssum[t - o] : 0;
        __syncthreads();
        ssum[t] += add;
        __syncthreads();
    }
    int excl = ssum[t] - v;           // exclusive over pairs
    int o0 = ebeg + excl;
    int o1 = o0 + c0;
    int n0 = (b << BSHIFT) + 2 * t;
    if (n0 < N_NODES) seg[n0] = o0;
    if (n0 + 1 < N_NODES) seg[n0 + 1] = o1;
    __syncthreads();                  // all cnt reads (c0,c1) retired
    cnt[2 * t] = o0;                  // reuse as cursors (global positions)
    cnt[2 * t + 1] = o1;
    __syncthreads();
    for (int e = ebeg + t; e < eend; e += 256) {
        int2 p = pp[e];
        int pos = atomicAdd(&cnt[p.x >> 17], 1);
        pe[pos] = make_int2(p.x & 0x1FFFF, p.y);
    }
    if (b == 0 && t == 0) seg[N_NODES] = N_EDGES;
}

// ---------------------------------------------------------------------------
// Fused layer (CSR): gather(+x, +input-BN-affine, wsum inline) -> LDS ->
// MLP1 -> relu -> MLP2 -> relu -> global write + per-block BN stat partials.
// Block = 256 threads = 4 waves, 64 nodes; node id wave-uniform in gather so
// edge (src,w) pairs are s_loads (4 contiguous int2 = s_load_dwordx8);
// x_in[src] row is one coalesced 256B load. Edge loop unrolled x4 with 4
// independent accumulators -> 4 outstanding gather loads per wave.
// Input BN affine folded: agg_bn = sc*(x[n]+Sum w*x[s]) + sh*(1+Sum w).
__global__ void __launch_bounds__(256) layer_kernel(
    const float* __restrict__ x_in, int xstride,
    const int* __restrict__ seg,     // CSR offsets (N+1)
    const int2* __restrict__ pe,
    const float* __restrict__ affine /* [128]: scale|shift of input */,
    const float* __restrict__ W1T, const float* __restrict__ b1,
    const float* __restrict__ W2T, const float* __restrict__ b2,
    float* __restrict__ out /* xs base + layer*64, row stride OUTD */,
    float* __restrict__ pstat /* [NLBLK][128]: sum|sumsq partials */) {
    __shared__ float lds[NPB * LDS_PITCH];
    int t = threadIdx.x;
    int lane = t & 63;
    int wid = __builtin_amdgcn_readfirstlane(t >> 6);   // wave id 0..3, SGPR
    int nbase = blockIdx.x * NPB;

    float sc_in = affine[lane];          // coalesced 256B, once
    float sh_in = affine[64 + lane];

    // ---- Phase 1: gather (16 nodes per wave, node id wave-uniform) ----
    for (int nn = 0; nn < 16; ++nn) {
        int n = nbase + wid * 16 + nn;
        float acc = 0.0f;
        if (n < N_NODES) {
            int beg = seg[n];
            int end = seg[n + 1];
            float a0 = x_in[(size_t)n * xstride + lane];   // coalesced 256B
            float a1 = 0.0f, a2 = 0.0f, a3 = 0.0f;
            float ws = 0.0f;                               // Sum edge weights
            int e = beg;
            for (; e + 4 <= end; e += 4) {
                int2 p0 = pe[e];
                int2 p1 = pe[e + 1];
                int2 p2 = pe[e + 2];
                int2 p3 = pe[e + 3];
                float w0 = __int_as_float(p0.y);
                float w1 = __int_as_float(p1.y);
                float w2 = __int_as_float(p2.y);
                float w3 = __int_as_float(p3.y);
                a0 = fmaf(w0, x_in[(size_t)p0.x * xstride + lane], a0);
                a1 = fmaf(w1, x_in[(size_t)p1.x * xstride + lane], a1);
                a2 = fmaf(w2, x_in[(size_t)p2.x * xstride + lane], a2);
                a3 = fmaf(w3, x_in[(size_t)p3.x * xstride + lane], a3);
                ws += (w0 + w1) + (w2 + w3);
            }
            for (; e < end; ++e) {
                int2 p = pe[e];
                float w = __int_as_float(p.y);
                a1 = fmaf(w, x_in[(size_t)p.x * xstride + lane], a1);
                ws += w;
            }
            acc = fmaf(sc_in, (a0 + a1) + (a2 + a3), sh_in * (1.0f + ws));
        }
        lds[(wid * 16 + nn) * LDS_PITCH + lane] = acc;
    }
    __syncthreads();

    // ---- Stage 1 GEMM: hidden = relu(xin @ W1^T + b1) ----
    float h[16];
#pragma unroll
    for (int jj = 0; jj < 16; ++jj) h[jj] = b1[wid * 16 + jj];
#pragma unroll 4
    for (int k = 0; k < DIM; ++k) {
        float xv = lds[lane * LDS_PITCH + k];
        const float* wr = W1T + k * DIM + wid * 16;   // uniform -> s_load
#pragma unroll
        for (int jj = 0; jj < 16; ++jj) h[jj] = fmaf(xv, wr[jj], h[jj]);
    }
#pragma unroll
    for (int jj = 0; jj < 16; ++jj) h[jj] = fmaxf(h[jj], 0.0f);
    __syncthreads();          // all lds (xin) reads done
#pragma unroll
    for (int jj = 0; jj < 16; ++jj) lds[lane * LDS_PITCH + wid * 16 + jj] = h[jj];
    __syncthreads();

    // ---- Stage 2 GEMM: o = relu(hidden @ W2^T + b2) ----
    float o[16];
#pragma unroll
    for (int jj = 0; jj < 16; ++jj) o[jj] = b2[wid * 16 + jj];
#pragma unroll 4
    for (int k = 0; k < DIM; ++k) {
        float hv = lds[lane * LDS_PITCH + k];
        const float* wr = W2T + k * DIM + wid * 16;
#pragma unroll
        for (int jj = 0; jj < 16; ++jj) o[jj] = fmaf(hv, wr[jj], o[jj]);
    }
    int n = nbase + lane;
    bool valid = (n < N_NODES);
#pragma unroll
    for (int jj = 0; jj < 16; ++jj) o[jj] = fmaxf(o[jj], 0.0f);
    if (valid) {
        float* orow = out + (size_t)n * OUTD + wid * 16;
#pragma unroll
        for (int jj = 0; jj < 16; jj += 4) {
            *(float4*)(orow + jj) = make_float4(o[jj], o[jj + 1], o[jj + 2], o[jj + 3]);
        }
    }

    // ---- BN stat partials: butterfly over 64 lanes; wave wid owns dims
    // [wid*16, wid*16+16). Non-atomic coalesced per-block store.
    float my_s = 0.0f, my_q = 0.0f;
#pragma unroll
    for (int jj = 0; jj < 16; ++jj) {
        float v = valid ? o[jj] : 0.0f;
        float vs = v, vq = v * v;
#pragma unroll
        for (int m = 1; m < 64; m <<= 1) {
            vs += __shfl_xor(vs, m);
            vq += __shfl_xor(vq, m);
        }
        if (lane == jj) { my_s = vs; my_q = vq; }
    }
    if (lane < 16) {
        size_t base = (size_t)blockIdx.x * 128 + wid * 16 + lane;
        pstat[base] = my_s;
        pstat[base + 64] = my_q;
    }
}

// ---------------------------------------------------------------------------
// Reduce per-block BN partials -> scale/shift (bn_prep folded).
// 8 blocks, block b owns dims [b*8, b*8+8); 16 groups of 16 threads stride
// over the 1563 pstat rows.
__global__ void __launch_bounds__(256) reduce_stats(
    const float* __restrict__ pstat,
    const float* __restrict__ gamma, const float* __restrict__ beta,
    float* __restrict__ ss /* [128]: scale|shift */) {
    __shared__ double part[16][16];
    int b = blockIdx.x;            // 0..7
    int t = threadIdx.x;
    int slot = t & 15;             // 0..7 -> sum(d), 8..15 -> sumsq(d)
    int g = t >> 4;                // group 0..15
    int d = b * 8 + (slot & 7);
    int off = (slot < 8) ? 0 : 64;
    double s = 0.0;
    for (int blk = g; blk < NLBLK; blk += 16)
        s += (double)pstat[(size_t)blk * 128 + off + d];
    part[g][slot] = s;
    __syncthreads();
    if (t < 16) {
        double x = 0.0;
#pragma unroll
        for (int k = 0; k < 16; ++k) x += part[k][t];
        part[0][t] = x;            // column t only -> no hazard
    }
    __syncthreads();
    if (t < 8) {
        int dd = b * 8 + t;
        double mu = part[0][t] / (double)N_NODES;
        double var = part[0][8 + t] / (double)N_NODES - mu * mu;
        float inv = (float)(1.0 / sqrt(var + (double)BN_EPS));
        float sc = gamma[dd] * inv;
        ss[dd] = sc;
        ss[64 + dd] = beta[dd] - (float)mu * sc;
    }
}

// ---------------------------------------------------------------------------
// Final pass: apply BN affine to xs IN PLACE (all 3 layers at once) and
// add-pool per graph. Grid (512 graphs, 4 parts), block 192.
__global__ void bn_pool(float* __restrict__ xs,
                        const int* __restrict__ batch,
                        const float* __restrict__ ss /* [3][128] */,
                        float* __restrict__ pooled) {
    int g = blockIdx.x;
    int part = blockIdx.y;   // 0..3
    int d = threadIdx.x;     // 0..191
    int l = d >> 6, dd = d & 63;
    float sc = ss[l * 128 + dd];
    float sh = ss[l * 128 + 64 + dd];
    int start, end;
    {
        int lo = 0, hi = N_NODES;
        while (lo < hi) { int m = (lo + hi) >> 1; if (batch[m] < g) lo = m + 1; else hi = m; }
        start = lo;
    }
    {
        int lo = start, hi = N_NODES;
        while (lo < hi) { int m = (lo + hi) >> 1; if (batch[m] <= g) lo = m + 1; else hi = m; }
        end = lo;
    }
    float acc = 0.0f;
    for (int n = start + part; n < end; n += 4) {
        float* p = xs + (size_t)n * OUTD + d;
        float v = fmaf(*p, sc, sh);
        *p = v;
        acc += v;
    }
    atomicAdd(&pooled[(size_t)g * OUTD + d], acc);
}

// ---------------------------------------------------------------------------
extern "C" void kernel_launch(void* const* d_in, const int* in_sizes, int n_in,
                              void* d_out, int out_size, void* d_ws, size_t ws_size,
                              hipStream_t stream) {
    const float* x0    = (const float*)d_in[0];
    const int*   ei    = (const int*)d_in[1];
    const float* ew    = (const float*)d_in[2];
    const int*   batch = (const int*)d_in[3];
    const float* W1    = (const float*)d_in[5];
    const float* b1    = (const float*)d_in[6];
    const float* W2    = (const float*)d_in[7];
    const float* b2    = (const float*)d_in[8];
    const float* gamma = (const float*)d_in[9];
    const float* beta  = (const float*)d_in[10];

    float* pooled = (float*)d_out;                      // [512, 192]
    float* xs     = pooled + (size_t)N_GRAPHS * OUTD;   // [100000, 192]

    const int* src = ei;
    const int* dst = ei + N_EDGES;

    // Workspace layout (all fits in ~21.5 MB; prior ELL path needed 39+):
    // pe[E] | pp[E] | seg[N+4] | hist[NPBLK*NBUK] | base[NPBLK*NBUK]
    // | bstart[NBUK+4] | W1T | W2T | idaff | ss | pstat
    int2*  pe     = (int2*)d_ws;
    int2*  pp     = pe + N_EDGES;
    int*   seg    = (int*)(pp + N_EDGES);
    int*   hist   = seg + N_NODES + 4;
    int*   pbase  = hist + (size_t)NPBLK * NBUK;
    int*   bstart = pbase + (size_t)NPBLK * NBUK;
    float* W1T    = (float*)(bstart + NBUK + 4);
    float* W2T    = W1T + N_LAYERS * DIM * DIM;
    float* idaff  = W2T + N_LAYERS * DIM * DIM;    // 128 floats
    float* ss     = idaff + 128;                   // 3*128 floats
    float* pstat  = ss + N_LAYERS * 128;           // NLBLK*128 floats

    transpose_w<<<(N_LAYERS * DIM * DIM + 255) / 256, 256, 0, stream>>>(
        W1, W2, W1T, W2T, idaff);

    // Two-level binning: contention-free partition -> per-bucket CSR.
    part_hist<<<NPBLK, 256, 0, stream>>>(dst, hist);
    part_scan<<<1, 256, 0, stream>>>(hist, pbase, bstart);
    part_scatter<<<NPBLK, 256, 0, stream>>>(src, dst, ew, pbase, pp);
    csr_build<<<NBUK, 256, 0, stream>>>(pp, bstart, seg, pe);

    for (int i = 0; i < N_LAYERS; ++i) {
        const float* xin = (i == 0) ? x0 : (xs + (size_t)(i - 1) * DIM);
        int xstride = (i == 0) ? DIM : OUTD;
        const float* affine = (i == 0) ? idaff : (ss + (size_t)(i - 1) * 128);

        layer_kernel<<<NLBLK, 256, 0, stream>>>(
            xin, xstride, seg, pe, affine,
            W1T + (size_t)i * DIM * DIM, b1 + (size_t)i * DIM,
            W2T + (size_t)i * DIM * DIM, b2 + (size_t)i * DIM,
            xs + (size_t)i * DIM, pstat);

        reduce_stats<<<8, 256, 0, stream>>>(
            pstat, gamma + (size_t)i * DIM, beta + (size_t)i * DIM,
            ss + (size_t)i * 128);
    }

    hipMemsetAsync(pooled, 0, (size_t)N_GRAPHS * OUTD * sizeof(float), stream);
    dim3 pgrid(N_GRAPHS, 4);
    bn_pool<<<pgrid, OUTD, 0, stream>>>(xs, batch, ss, pooled);
}